// Round 8
// baseline (1343.436 us; speedup 1.0000x reference)
//
#include <hip/hip_runtime.h>
#include <hip/hip_bf16.h>

#define D 100
#define XS 128   // padded row stride (elements) for all activation buffers

typedef __hip_bfloat16 bf16;
typedef __attribute__((ext_vector_type(8))) short bf16x8;
typedef __attribute__((ext_vector_type(4))) float f32x4;

__device__ __forceinline__ float ldf(const void* p, long long i, int f32) {
    return f32 ? ((const float*)p)[i] : __bfloat162float(((const bf16*)p)[i]);
}

__device__ __forceinline__ float b2f(unsigned short u) {
    return __uint_as_float(((unsigned int)u) << 16);
}

__device__ __forceinline__ unsigned short f2bu(float x) {
    union { bf16 b; unsigned short u; } cv;
    cv.b = __float2bfloat16(x);
    return cv.u;
}

// ---------- input dtype detector: 0 = bf16, 1 = fp32 ----------
__global__ void detectk(const void* __restrict__ emb, int* __restrict__ flag)
{
    const unsigned short* u = (const unsigned short*)emb;
    __shared__ int cnt;
    if (threadIdx.x == 0) cnt = 0;
    __syncthreads();
    int good = 0;
    for (int i = threadIdx.x; i < 512; i += 256) {
        int e = (u[i] >> 7) & 0xFF;
        if (e >= 118 && e <= 137) good++;
    }
    atomicAdd(&cnt, good);
    __syncthreads();
    if (threadIdx.x == 0) *flag = (cnt >= 410) ? 0 : 1;
}

// ---------- weight prep: 5 matrices -> transposed, padded [112][128], hi/lo bf16 ----
// Wt[c][k] = W[k][c]; hi = bf16(w), lo = bf16(w - hi). Pad region = 0 exactly,
// so MFMA outputs for cols 100..111 are exact zeros (pad-invariant trick).

__global__ void wprep(const void* __restrict__ wi, const void* __restrict__ w1,
    const void* __restrict__ w2, const int* __restrict__ flag,
    bf16* __restrict__ wh, bf16* __restrict__ wl)
{
    int i = blockIdx.x * 256 + threadIdx.x;
    if (i >= 5 * 112 * 128) return;
    int m = i / (112 * 128), rem = i - m * (112 * 128);
    int c = rem / 128, k = rem - c * 128;
    float w = 0.f;
    if (c < D && k < D) {
        int f = *flag;
        long long si = (long long)k * D + c;
        if (m < 3)       w = ldf(wi, m * 10000 + si, f);
        else if (m == 3) w = ldf(w1, si, f);
        else             w = ldf(w2, si, f);
    }
    bf16 hb = __float2bfloat16(w);
    wh[i] = hb;
    wl[i] = __float2bfloat16(w - __bfloat162float(hb));
}

// initk: writes FULL padded rows (pads = 0); o0 pre-scaled by 0.25.
__global__ void initk(const void* __restrict__ emb, const int* __restrict__ flag,
    bf16* __restrict__ x, float* __restrict__ o0, float* __restrict__ o1, int n)
{
    long long i = (long long)blockIdx.x * 256 + threadIdx.x;
    if (i >= (long long)n * XS) return;
    int nn = (int)(i >> 7), d = (int)(i & 127);
    float v = 0.f;
    if (d < D) v = ldf(emb, (long long)nn * D + d, *flag);
    x[i] = __float2bfloat16(v);
    if (d < D) {
        o0[(long long)nn * D + d] = v * 0.25f;
        o1[(long long)nn * D + d] = 0.0f;
    }
}

// ---------- GEMM building blocks ----------
// All GEMMs: 32 rows/wave (3125 waves = 3/SIMD for latency hiding), 4 waves/blk.
// A-frag: row = lane&15, k = (lane>>4)*8 + j. C/D: col = lane&15,
// row = (lane>>4)*4 + reg [measured m89/m91]. Row-wide reduces via shfl_xor
// 1/2/4/8 within the r16 group. Rows >= n read guard garbage; MFMA keeps
// garbage in its own C row; all global stores / o-accums are row-guarded.

#define MFMA_K_LOOP(XPTR, WHP, WLP, ACC)                                          \
    {                                                                             \
        const bf16* xa_ = (XPTR);                                                 \
        _Pragma("unroll")                                                         \
        for (int ks = 0; ks < 4; ++ks) {                                          \
            bf16x8 a0 = *(const bf16x8*)(xa_ + ks * 32);                          \
            bf16x8 a1 = *(const bf16x8*)(xa_ + 16 * XS + ks * 32);                \
            _Pragma("unroll")                                                     \
            for (int nt = 0; nt < 7; ++nt) {                                      \
                const bf16* wb = (WHP) + (nt * 16 + r16) * 128 + ks * 32 + kg * 8;\
                bf16x8 bh = *(const bf16x8*)wb;                                   \
                bf16x8 bl = *(const bf16x8*)(wb + ((WLP) - (WHP)));               \
                ACC[0][nt] = __builtin_amdgcn_mfma_f32_16x16x32_bf16(a0, bh, ACC[0][nt], 0, 0, 0); \
                ACC[0][nt] = __builtin_amdgcn_mfma_f32_16x16x32_bf16(a0, bl, ACC[0][nt], 0, 0, 0); \
                ACC[1][nt] = __builtin_amdgcn_mfma_f32_16x16x32_bf16(a1, bh, ACC[1][nt], 0, 0, 0); \
                ACC[1][nt] = __builtin_amdgcn_mfma_f32_16x16x32_bf16(a1, bl, ACC[1][nt], 0, 0, 0); \
            }                                                                     \
        }                                                                         \
    }

// gemm0: B2 = X@W (plain; no pad stores — B2 feeds spmm which reads cols<100)
__global__ __launch_bounds__(256) void gemm0(
    const bf16* __restrict__ X, const bf16* __restrict__ Wh,
    const bf16* __restrict__ Wl, bf16* __restrict__ Y, int n)
{
    const int wave = threadIdx.x >> 6, lane = threadIdx.x & 63;
    const int r16 = lane & 15, kg = lane >> 4;
    const long long m0 = ((long long)blockIdx.x * 4 + wave) * 32;

    f32x4 acc[2][7];
    #pragma unroll
    for (int i = 0; i < 2; ++i)
        #pragma unroll
        for (int j = 0; j < 7; ++j) acc[i][j] = (f32x4){0.f, 0.f, 0.f, 0.f};

    MFMA_K_LOOP(X + (m0 + r16) * XS + kg * 8, Wh, Wl, acc);

    #pragma unroll
    for (int rt = 0; rt < 2; ++rt)
        #pragma unroll
        for (int nt = 0; nt < 7; ++nt) {
            int col = nt * 16 + r16;
            #pragma unroll
            for (int r = 0; r < 4; ++r) {
                long long row = m0 + rt * 16 + kg * 4 + r;
                if (row < n) Y[row * XS + col] = __float2bfloat16(acc[rt][nt][r]);
            }
        }
}

// gemm12: H1 = row_softmax( relu(X@W1 + X) @ W2 )
// The relu intermediate lives only in a per-wave LDS tile (stride 136 bf16 =
// 272 B -> banks shift by 4 per row: ds_read_b128 A-frags are conflict-free).
__global__ __launch_bounds__(256) void gemm12(
    const bf16* __restrict__ X,
    const bf16* __restrict__ W1h, const bf16* __restrict__ W1l,
    const bf16* __restrict__ W2h, const bf16* __restrict__ W2l,
    bf16* __restrict__ H1, int n)
{
    __shared__ ushort tile[4][32][136];
    const int wave = threadIdx.x >> 6, lane = threadIdx.x & 63;
    const int r16 = lane & 15, kg = lane >> 4;
    const long long m0 = ((long long)blockIdx.x * 4 + wave) * 32;

    f32x4 acc[2][7];
    #pragma unroll
    for (int i = 0; i < 2; ++i)
        #pragma unroll
        for (int j = 0; j < 7; ++j) acc[i][j] = (f32x4){0.f, 0.f, 0.f, 0.f};

    MFMA_K_LOOP(X + (m0 + r16) * XS + kg * 8, W1h, W1l, acc);

    // epilogue 1: relu(acc + X) -> LDS tile (bf16-rounded, identical numerics
    // to the old B2 materialization)
    #pragma unroll
    for (int rt = 0; rt < 2; ++rt)
        #pragma unroll
        for (int nt = 0; nt < 7; ++nt) {
            int col = nt * 16 + r16;
            #pragma unroll
            for (int r = 0; r < 4; ++r) {
                long long row = m0 + rt * 16 + kg * 4 + r;
                float v = acc[rt][nt][r] + __bfloat162float(X[row * XS + col]);
                tile[wave][rt * 16 + kg * 4 + r][col] = f2bu(fmaxf(v, 0.f));
            }
        }
    // zero LDS cols 112..127 (cols 100..111 are exact 0 via W/residual pads)
    {
        int rr = lane >> 1, half = lane & 1;
        *(int4*)&tile[wave][rr][112 + half * 8] = make_int4(0, 0, 0, 0);
    }

    // phase 2: A-frags from own LDS tile (compiler inserts lgkmcnt waits)
    f32x4 ac2[2][7];
    #pragma unroll
    for (int i = 0; i < 2; ++i)
        #pragma unroll
        for (int j = 0; j < 7; ++j) ac2[i][j] = (f32x4){0.f, 0.f, 0.f, 0.f};

    #pragma unroll
    for (int ks = 0; ks < 4; ++ks) {
        bf16x8 a0 = *(const bf16x8*)&tile[wave][r16][ks * 32 + kg * 8];
        bf16x8 a1 = *(const bf16x8*)&tile[wave][16 + r16][ks * 32 + kg * 8];
        #pragma unroll
        for (int nt = 0; nt < 7; ++nt) {
            const bf16* wb = W2h + (nt * 16 + r16) * 128 + ks * 32 + kg * 8;
            bf16x8 bh = *(const bf16x8*)wb;
            bf16x8 bl = *(const bf16x8*)(wb + (W2l - W2h));
            ac2[0][nt] = __builtin_amdgcn_mfma_f32_16x16x32_bf16(a0, bh, ac2[0][nt], 0, 0, 0);
            ac2[0][nt] = __builtin_amdgcn_mfma_f32_16x16x32_bf16(a0, bl, ac2[0][nt], 0, 0, 0);
            ac2[1][nt] = __builtin_amdgcn_mfma_f32_16x16x32_bf16(a1, bh, ac2[1][nt], 0, 0, 0);
            ac2[1][nt] = __builtin_amdgcn_mfma_f32_16x16x32_bf16(a1, bl, ac2[1][nt], 0, 0, 0);
        }
    }

    // softmax epilogue -> H1 (cols 100..111 get 0; pads 112..127 zeroed below)
    const bool v6 = (r16 < 4);
    #pragma unroll
    for (int rt = 0; rt < 2; ++rt)
        #pragma unroll
        for (int r = 0; r < 4; ++r) {
            float m = -3.0e38f;
            #pragma unroll
            for (int nt = 0; nt < 7; ++nt)
                if (nt < 6 || v6) m = fmaxf(m, ac2[rt][nt][r]);
            m = fmaxf(m, __shfl_xor(m, 1));
            m = fmaxf(m, __shfl_xor(m, 2));
            m = fmaxf(m, __shfl_xor(m, 4));
            m = fmaxf(m, __shfl_xor(m, 8));
            float ex[7]; float s = 0.f;
            #pragma unroll
            for (int nt = 0; nt < 7; ++nt) {
                ex[nt] = (nt < 6 || v6) ? __expf(ac2[rt][nt][r] - m) : 0.f;
                s += ex[nt];
            }
            s += __shfl_xor(s, 1);
            s += __shfl_xor(s, 2);
            s += __shfl_xor(s, 4);
            s += __shfl_xor(s, 8);
            float inv = 1.f / s;
            long long row = m0 + rt * 16 + kg * 4 + r;
            if (row < n) {
                #pragma unroll
                for (int nt = 0; nt < 7; ++nt)
                    H1[row * XS + nt * 16 + r16] = __float2bfloat16(ex[nt] * inv);
            }
        }
    // H1 pads 112..127 must be 0 (H1 is read as A-frags by gemm30)
    {
        int rr = lane >> 1, half = lane & 1;
        long long row = m0 + rr;
        if (row < n)
            *(int4*)(H1 + row * XS + 112 + half * 8) = make_int4(0, 0, 0, 0);
    }
}

// gemm30: hn = H1@hsmT; xn = hn + X2; o0 += 0.25*xn/||xn||; o1 += (1/3)*hn/||hn||.
// CHAIN=1: additionally B2 = xn@Wnext via LDS tile (x_new never hits HBM).
// CHAIN=0 (last layer): epilogue only.
template<int CHAIN>
__global__ __launch_bounds__(256) void gemm30(
    const bf16* __restrict__ H1,
    const bf16* __restrict__ Hh, const bf16* __restrict__ Hl,
    const bf16* __restrict__ X2,
    const bf16* __restrict__ Wnh, const bf16* __restrict__ Wnl,
    bf16* __restrict__ B2out, int n,
    float* __restrict__ o0, float* __restrict__ o1)
{
    __shared__ ushort tile[CHAIN ? 4 : 1][32][136];
    const int wave = threadIdx.x >> 6, lane = threadIdx.x & 63;
    const int r16 = lane & 15, kg = lane >> 4;
    const long long m0 = ((long long)blockIdx.x * 4 + wave) * 32;

    f32x4 acc[2][7];
    #pragma unroll
    for (int i = 0; i < 2; ++i)
        #pragma unroll
        for (int j = 0; j < 7; ++j) acc[i][j] = (f32x4){0.f, 0.f, 0.f, 0.f};

    MFMA_K_LOOP(H1 + (m0 + r16) * XS + kg * 8, Hh, Hl, acc);

    #pragma unroll
    for (int rt = 0; rt < 2; ++rt)
        #pragma unroll
        for (int r = 0; r < 4; ++r) {
            long long row = m0 + rt * 16 + kg * 4 + r;
            float xn[7], hn[7];
            float sx = 0.f, sh2 = 0.f;
            #pragma unroll
            for (int nt = 0; nt < 7; ++nt) {
                int col = nt * 16 + r16;
                float h = acc[rt][nt][r];
                float x2v = __bfloat162float(X2[row * XS + col]);
                float xv = h + x2v;
                xn[nt] = xv; hn[nt] = h;
                sx += xv * xv; sh2 += h * h;    // pad cols contribute exact 0
            }
            sx  += __shfl_xor(sx, 1);  sx  += __shfl_xor(sx, 2);
            sx  += __shfl_xor(sx, 4);  sx  += __shfl_xor(sx, 8);
            sh2 += __shfl_xor(sh2, 1); sh2 += __shfl_xor(sh2, 2);
            sh2 += __shfl_xor(sh2, 4); sh2 += __shfl_xor(sh2, 8);
            float ia = 0.25f       / fmaxf(sqrtf(sx), 1e-12f);
            float ib = (1.f / 3.f) / fmaxf(sqrtf(sh2), 1e-12f);
            if (row < n) {
                long long bo = row * D;
                #pragma unroll
                for (int nt = 0; nt < 7; ++nt) {
                    int col = nt * 16 + r16;
                    if (col < D) {
                        o0[bo + col] += xn[nt] * ia;
                        o1[bo + col] += hn[nt] * ib;
                    }
                }
            }
            if (CHAIN) {
                #pragma unroll
                for (int nt = 0; nt < 7; ++nt)
                    tile[wave][rt * 16 + kg * 4 + r][nt * 16 + r16] = f2bu(xn[nt]);
            }
        }

    if (CHAIN) {
        {
            int rr = lane >> 1, half = lane & 1;
            *(int4*)&tile[wave][rr][112 + half * 8] = make_int4(0, 0, 0, 0);
        }
        f32x4 ac2[2][7];
        #pragma unroll
        for (int i = 0; i < 2; ++i)
            #pragma unroll
            for (int j = 0; j < 7; ++j) ac2[i][j] = (f32x4){0.f, 0.f, 0.f, 0.f};

        #pragma unroll
        for (int ks = 0; ks < 4; ++ks) {
            bf16x8 a0 = *(const bf16x8*)&tile[wave][r16][ks * 32 + kg * 8];
            bf16x8 a1 = *(const bf16x8*)&tile[wave][16 + r16][ks * 32 + kg * 8];
            #pragma unroll
            for (int nt = 0; nt < 7; ++nt) {
                const bf16* wb = Wnh + (nt * 16 + r16) * 128 + ks * 32 + kg * 8;
                bf16x8 bh = *(const bf16x8*)wb;
                bf16x8 bl = *(const bf16x8*)(wb + (Wnl - Wnh));
                ac2[0][nt] = __builtin_amdgcn_mfma_f32_16x16x32_bf16(a0, bh, ac2[0][nt], 0, 0, 0);
                ac2[0][nt] = __builtin_amdgcn_mfma_f32_16x16x32_bf16(a0, bl, ac2[0][nt], 0, 0, 0);
                ac2[1][nt] = __builtin_amdgcn_mfma_f32_16x16x32_bf16(a1, bh, ac2[1][nt], 0, 0, 0);
                ac2[1][nt] = __builtin_amdgcn_mfma_f32_16x16x32_bf16(a1, bl, ac2[1][nt], 0, 0, 0);
            }
        }
        #pragma unroll
        for (int rt = 0; rt < 2; ++rt)
            #pragma unroll
            for (int nt = 0; nt < 7; ++nt) {
                int col = nt * 16 + r16;
                #pragma unroll
                for (int r = 0; r < 4; ++r) {
                    long long row = m0 + rt * 16 + kg * 4 + r;
                    if (row < n)
                        B2out[row * XS + col] = __float2bfloat16(ac2[rt][nt][r]);
                }
            }
    }
}

// ---------- CSR construction (rebuilt per launch; workspace is re-poisoned) ----------

__global__ void hist(const int* __restrict__ rows, const int* __restrict__ cols,
    int* __restrict__ cnt, int n, int nnz)
{
    int e = blockIdx.x * 256 + threadIdx.x;
    if (e >= nnz) return;
    int r = rows[e], c = cols[e];
    if ((unsigned)r >= (unsigned)n || (unsigned)c >= (unsigned)n) return;
    atomicAdd(&cnt[r], 1);
}

__global__ void scan1(const int* __restrict__ cnt, int* __restrict__ offs,
    int* __restrict__ bsum, int n)
{
    __shared__ int sh[256];
    int b = blockIdx.x, t = threadIdx.x;
    int base = b * 2048 + t * 8;
    int v[8];
    int s = 0;
    #pragma unroll
    for (int i = 0; i < 8; ++i) {
        int idx = base + i;
        v[i] = (idx < n) ? cnt[idx] : 0;
        s += v[i];
    }
    sh[t] = s; __syncthreads();
    for (int off = 1; off < 256; off <<= 1) {
        int x = (t >= off) ? sh[t - off] : 0;
        __syncthreads();
        sh[t] += x;
        __syncthreads();
    }
    int run = sh[t] - s;
    #pragma unroll
    for (int i = 0; i < 8; ++i) {
        run += v[i];
        int idx = base + i;
        if (idx < n) offs[idx + 1] = run;
    }
    if (t == 255) bsum[b] = sh[255];
}

__global__ void scan2(int* __restrict__ bsum, int nb)
{
    __shared__ int sh[256];
    int t = threadIdx.x;
    int v = (t < nb) ? bsum[t] : 0;
    sh[t] = v; __syncthreads();
    for (int off = 1; off < 256; off <<= 1) {
        int x = (t >= off) ? sh[t - off] : 0;
        __syncthreads();
        sh[t] += x;
        __syncthreads();
    }
    if (t < nb) bsum[t] = sh[t] - v;
}

__global__ void scan3(int* __restrict__ offs, const int* __restrict__ bsum, int n)
{
    int i = blockIdx.x * 256 + threadIdx.x;
    if (i == 0) offs[0] = 0;
    if (i < n) offs[i + 1] += bsum[i >> 11];
}

__global__ void scatter(const int* __restrict__ rows, const int* __restrict__ cols,
    const void* __restrict__ vals, const int* __restrict__ flag,
    const int* __restrict__ offs, int* __restrict__ fill, int2* __restrict__ ecv,
    int n, int nnz)
{
    int e = blockIdx.x * 256 + threadIdx.x;
    if (e >= nnz) return;
    int r = rows[e], c = cols[e];
    if ((unsigned)r >= (unsigned)n || (unsigned)c >= (unsigned)n) return;
    int pos = offs[r] + atomicAdd(&fill[r], 1);
    float v = ldf(vals, e, *flag);
    ecv[pos] = make_int2(c, __float_as_int(v));
}

// ---------- CSR SpMM: one wave per row, no atomics; 8 gathers in flight ----------

__global__ void spmm_csr(const int* __restrict__ offs, const int2* __restrict__ ecv,
    const bf16* __restrict__ X, bf16* __restrict__ Y, int n)
{
    int wid = (int)(((long long)blockIdx.x * 256 + threadIdx.x) >> 6);
    int lane = threadIdx.x & 63;
    if (wid >= n) return;
    int s = offs[wid], e = offs[wid + 1];
    int d0 = lane * 2;
    if (d0 >= D) return;
    float a0 = 0.f, a1 = 0.f;
    int j = s;
    for (; j + 7 < e; j += 8) {
        int2 cv[8];
        unsigned int u[8];
        #pragma unroll
        for (int q = 0; q < 8; ++q) cv[q] = ecv[j + q];
        #pragma unroll
        for (int q = 0; q < 8; ++q)
            u[q] = *(const unsigned int*)(X + (long long)cv[q].x * XS + d0);
        #pragma unroll
        for (int q = 0; q < 8; ++q) {
            float v = __int_as_float(cv[q].y);
            a0 = fmaf(v, b2f((unsigned short)u[q]), a0);
            a1 = fmaf(v, b2f((unsigned short)(u[q] >> 16)), a1);
        }
    }
    for (; j < e; ++j) {
        int2 cv = ecv[j];
        unsigned int u = *(const unsigned int*)(X + (long long)cv.x * XS + d0);
        float v = __int_as_float(cv.y);
        a0 = fmaf(v, b2f((unsigned short)u), a0);
        a1 = fmaf(v, b2f((unsigned short)(u >> 16)), a1);
    }
    *(unsigned int*)(Y + (long long)wid * XS + d0) =
        ((unsigned int)f2bu(a1) << 16) | f2bu(a0);
}

// ---------- hsm: per-block TRANSPOSED partials + fused reduce/convert ----------
// partials[b][dd*100+kk] so hsm_rc reads are coalesced (consecutive k).

#define HSM_G 512
#define HSM_BATCH 32

__global__ void hsm_partial(const bf16* __restrict__ H1, const bf16* __restrict__ X2,
    float* __restrict__ partials, int n)
{
    __shared__ float sh[HSM_BATCH][D];   // H1 rows (k)
    __shared__ float sx[HSM_BATCH][D];   // X2 rows (d)
    const int t = threadIdx.x;
    const int tk = t / 10;               // 0..24 active (t < 250)
    const int td = t - tk * 10;          // 0..9

    float acc[4][10];
    #pragma unroll
    for (int i = 0; i < 4; ++i)
        #pragma unroll
        for (int j = 0; j < 10; ++j) acc[i][j] = 0.f;

    const int per = (n + HSM_G - 1) / HSM_G;
    const int s = blockIdx.x * per;
    int e = s + per; if (e > n) e = n;

    for (int base = s; base < e; base += HSM_BATCH) {
        int cnt = e - base; if (cnt > HSM_BATCH) cnt = HSM_BATCH;
        __syncthreads();
        for (int v = t; v < cnt * 25; v += 256) {
            int r = v / 25, c4 = v - (v / 25) * 25;
            ushort4 h4 = *(const ushort4*)(H1 + (long long)(base + r) * XS + 4 * c4);
            ushort4 x4 = *(const ushort4*)(X2 + (long long)(base + r) * XS + 4 * c4);
            sh[r][4 * c4 + 0] = b2f(h4.x);
            sh[r][4 * c4 + 1] = b2f(h4.y);
            sh[r][4 * c4 + 2] = b2f(h4.z);
            sh[r][4 * c4 + 3] = b2f(h4.w);
            sx[r][4 * c4 + 0] = b2f(x4.x);
            sx[r][4 * c4 + 1] = b2f(x4.y);
            sx[r][4 * c4 + 2] = b2f(x4.z);
            sx[r][4 * c4 + 3] = b2f(x4.w);
        }
        __syncthreads();
        if (t < 250) {
            #pragma unroll 8
            for (int r = 0; r < cnt; ++r) {
                float4 a = *(const float4*)&sh[r][tk * 4];
                const float2* bp = (const float2*)&sx[r][td * 10];  // 8B-aligned
                float2 b0 = bp[0], b1 = bp[1], b2 = bp[2], b3 = bp[3], b4 = bp[4];
                float b[10] = {b0.x, b0.y, b1.x, b1.y, b2.x, b2.y, b3.x, b3.y, b4.x, b4.y};
                #pragma unroll
                for (int j = 0; j < 10; ++j) {
                    acc[0][j] = fmaf(a.x, b[j], acc[0][j]);
                    acc[1][j] = fmaf(a.y, b[j], acc[1][j]);
                    acc[2][j] = fmaf(a.z, b[j], acc[2][j]);
                    acc[3][j] = fmaf(a.w, b[j], acc[3][j]);
                }
            }
        }
    }

    if (t < 250) {
        float* out = partials + (long long)blockIdx.x * (D * D);
        #pragma unroll
        for (int i = 0; i < 4; ++i)
            #pragma unroll
            for (int j = 0; j < 10; ++j)
                out[(td * 10 + j) * D + (tk * 4 + i)] = acc[i][j];   // TRANSPOSED
    }
}

// fused: sum transposed partials + hi/lo convert into GEMM B-layout [112][128]
__global__ void hsm_rc(const float* __restrict__ P, bf16* __restrict__ hh,
    bf16* __restrict__ hl)
{
    int i = blockIdx.x * 256 + threadIdx.x;
    if (i >= 112 * 128) return;
    int c = i >> 7, k = i & 127;        // Wt[c=dd][k=kk] = hsm[kk][dd]
    float w = 0.f;
    if (c < D && k < D) {
        const float* p = P + c * D + k; // partials[b][dd*100+kk] -> coalesced
        float s0 = 0.f, s1 = 0.f;
        for (int b = 0; b < HSM_G; b += 2) {
            s0 += p[(long long)b * (D * D)];
            s1 += p[(long long)(b + 1) * (D * D)];
        }
        w = s0 + s1;
    }
    bf16 hb = __float2bfloat16(w);
    hh[i] = hb;
    hl[i] = __float2bfloat16(w - __bfloat162float(hb));
}

// ---------- host ----------

extern "C" void kernel_launch(void* const* d_in, const int* in_sizes, int n_in,
                              void* d_out, int out_size, void* d_ws, size_t ws_size,
                              hipStream_t stream)
{
    const void* emb   = d_in[0];
    // d_in[1] = adj: cancels exactly in column-normalization (softmax rows sum to 1)
    const void* evals = d_in[2];
    const void* Wit   = d_in[3];
    const void* Wi1   = d_in[4];
    const void* Wi2   = d_in[5];
    const int* erows  = (const int*)d_in[6];
    const int* ecols  = (const int*)d_in[7];
    const int N   = in_sizes[0] / D;
    const int NNZ = in_sizes[2];
    const long long ND = (long long)N * D;
    const size_t NB = (size_t)N * XS * 2;   // padded activation buffer bytes

    float* o0 = (float*)d_out;      // item_embeddings accumulator (fp32 output!)
    float* o1 = o0 + ND;            // hs accumulator

    char* base = (char*)d_ws;
    size_t off = 0;
    auto alloc = [&](size_t bytes) -> void* {
        void* r = base + off;
        off += (bytes + 255) & ~(size_t)255;
        return r;
    };
    int*   flag  = (int*)  alloc(256);
    bf16*  WH    = (bf16*) alloc(5 * 112 * 128 * 2);
    bf16*  WL    = (bf16*) alloc(5 * 112 * 128 * 2);
    bf16*  hsmTh = (bf16*) alloc(112 * 128 * 2);
    bf16*  hsmTl = (bf16*) alloc(112 * 128 * 2);
    int*   offs  = (int*)  alloc(((size_t)N + 1) * 4);
    int*   cnt   = (int*)  alloc((size_t)N * 4);        // reused as scatter fill
    int*   bsum  = (int*)  alloc(1024);
    int2*  ecv   = (int2*) alloc((size_t)NNZ * 8);
    bf16*  B1    = (bf16*) alloc(NB);
    bf16*  B2    = (bf16*) alloc(NB);
    bf16*  H1    = (bf16*) alloc(NB);
    (void)alloc(128 * XS * 2);   // guard: 128-row blocks may read past last buffer
    // partials (512 * 40 KB = 20.5 MB) alias B2: B2 is dead between spmm (its
    // consumer) and gemm30's chain output.
    float* partials = (float*)B2;

    const int gNX = (int)(((long long)N * XS + 255) / 256);
    const int gE  = (NNZ + 255) / 256;
    const int nb  = (N + 2047) / 2048;
    const int gM  = (N + 127) / 128;          // 4-wave blocks, 32 rows/wave
    const int gS  = (N + 3) / 4;              // spmm: 4 waves per block

    detectk<<<1, 256, 0, stream>>>(emb, flag);
    wprep<<<(5 * 112 * 128 + 255) / 256, 256, 0, stream>>>(Wit, Wi1, Wi2, flag, WH, WL);
    initk<<<gNX, 256, 0, stream>>>(emb, flag, B1, o0, o1, N);

    // ---- one-time CSR build ----
    hipMemsetAsync(cnt, 0, (size_t)N * 4, stream);
    hist<<<gE, 256, 0, stream>>>(erows, ecols, cnt, N, NNZ);
    scan1<<<nb, 256, 0, stream>>>(cnt, offs, bsum, N);
    scan2<<<1, 256, 0, stream>>>(bsum, nb);
    scan3<<<(N + 255) / 256, 256, 0, stream>>>(offs, bsum, N);
    hipMemsetAsync(cnt, 0, (size_t)N * 4, stream);
    scatter<<<gE, 256, 0, stream>>>(erows, ecols, evals, flag, offs, cnt, ecv, N, NNZ);

    // layer 0 entry: B2 = x0 @ W_item[0]
    gemm0<<<gM, 256, 0, stream>>>(B1, WH, WL, B2, N);

    for (int l = 0; l < 3; ++l) {
        spmm_csr<<<gS, 256, 0, stream>>>(offs, ecv, B2, B1, N);      // B1 = x2
        gemm12<<<gM, 256, 0, stream>>>(B1, WH + 3 * 14336, WL + 3 * 14336,
                                       WH + 4 * 14336, WL + 4 * 14336, H1, N);
        hsm_partial<<<HSM_G, 256, 0, stream>>>(H1, B1, partials, N); // partials=B2
        hsm_rc<<<(112 * 128 + 255) / 256, 256, 0, stream>>>(partials, hsmTh, hsmTl);
        if (l < 2)
            gemm30<1><<<gM, 256, 0, stream>>>(H1, hsmTh, hsmTl, B1,
                WH + (l + 1) * 14336, WL + (l + 1) * 14336, B2, N, o0, o1);
        else
            gemm30<0><<<gM, 256, 0, stream>>>(H1, hsmTh, hsmTl, B1,
                nullptr, nullptr, nullptr, N, o0, o1);
    }
}